// Round 1
// 73.250 us; speedup vs baseline: 1.0830x; 1.0830x over previous
//
#include <hip/hip_runtime.h>

// Depth-4 path signature, B=128, L=128, C=12, fp32.
// Round 6: single fused kernel; ALL increment data lives in LDS.
//   - R5's per-iteration s_load_dwordx16 trio read prep-written global
//     memory: every iteration was a fresh-64B-line K$ miss (likely a
//     cross-XCD dirty-line read, ~600-1000 cyc), serialized by the
//     lgkmcnt(0) full drain, with only ~2 waves/SIMD to hide it.
//   - Now: stage path (coalesced float4) -> LDS, build increments in LDS
//     in BOTH layouts: row-major W[s][c] for the block-uniform broadcast
//     operand (wave-uniform address -> LDS broadcast, conflict-free) and
//     transposed DT4[c][sq] (<=2-way conflicts = free) for per-thread reads.
//   - Main loop: zero global traffic, zero scalar loads, no barriers;
//     compiler emits fine-grained lgkmcnt for ds_read->use.
//   - No workspace, one kernel launch (prep is fused).

#define NC    12
#define NPTS  128
#define NSTEP 128            // 127 real increments + 1 zero pad (identity)
#define OUT_PER_B 22620      // 12 + 144 + 1728 + 20736
#define BT 448               // 432 active = 6(i) * 12(j) * 6(k-pairs)
#define PADQ 33              // float4 row stride in transposed LDS table

__global__ __launch_bounds__(BT)
void sig_kernel(const float* __restrict__ path, float* __restrict__ out) {
    const int bid = blockIdx.x;
    const int b  = bid >> 1;
    const int ih = bid & 1;
    const int t  = threadIdx.x;

    __shared__ __align__(16) float  P[NPTS * NC];     // 6144 B staged path
    __shared__ __align__(16) float  W[NSTEP * NC];    // 6144 B row-major [s][c]
    __shared__ __align__(16) float4 DT4[NC * PADQ];   // 6336 B transposed [c][sq]

    // ---- stage path, coalesced (384 float4 = 6 KB) ----
    const float* pb = path + (size_t)b * (NPTS * NC);
    if (t < 384) ((float4*)P)[t] = ((const float4*)pb)[t];
    __syncthreads();

    // ---- increments into both LDS layouts (one-time; conflicts don't matter) ----
    if (t < 384) {
        const int c  = t >> 5;        // 0..11
        const int sq = t & 31;        // 0..31
        float d[4];
        #pragma unroll
        for (int e = 0; e < 4; ++e) {
            const int s = 4 * sq + e;
            d[e] = (s < NPTS - 1) ? (P[(s + 1) * NC + c] - P[s * NC + c]) : 0.f;
            W[s * NC + c] = d[e];
        }
        DT4[c * PADQ + sq] = make_float4(d[0], d[1], d[2], d[3]);
    }
    __syncthreads();

    // ---- index map (pad threads duplicate work; stores guarded later) ----
    const int ta  = (t < 432) ? t : (t - 432);
    const int il  = ta / 72;
    const int rem = ta - il * 72;
    const int j   = rem / 6;
    const int kh  = rem - j * 6;
    const int i   = ih * 6 + il;
    const int k0  = kh * 2;

    float acc0[12], acc1[12];
    #pragma unroll
    for (int l = 0; l < 12; ++l) { acc0[l] = 0.f; acc1[l] = 0.f; }
    float s3a = 0.f, s3b = 0.f, s2 = 0.f, s1 = 0.f;

    const float4* wt   = (const float4*)W;        // 12 float4 per sq group
    const float4* dti  = &DT4[i * PADQ];
    const float4* dtj  = &DT4[j * PADQ];
    const float4* dtka = &DT4[k0 * PADQ];
    const float4* dtkb = &DT4[(k0 + 1) * PADQ];

    for (int sq = 0; sq < NSTEP / 4; ++sq) {
        // block-uniform 48 increments for these 4 steps: LDS broadcast reads
        float4 wq[12];
        #pragma unroll
        for (int q = 0; q < 12; ++q) wq[q] = wt[sq * 12 + q];

        // per-thread transposed reads (<=2-way conflict = free)
        float4 di4  = dti[sq];
        float4 dj4  = dtj[sq];
        float4 dka4 = dtka[sq];
        float4 dkb4 = dtkb[sq];

        #pragma unroll
        for (int u = 0; u < 4; ++u) {
            const float di  = (&di4.x)[u];
            const float dj  = (&dj4.x)[u];
            const float dka = (&dka4.x)[u];
            const float dkb = (&dkb4.x)[u];

            // Horner-factored Chen step (identical arithmetic to R2..R5)
            float A4  = (s1 + 0.25f * di) * (1.f / 3.f);
            float B4  = (s2 + dj * A4) * 0.5f;
            float C3a = s3a + dka * B4;
            float C3b = s3b + dkb * B4;

            #pragma unroll
            for (int l = 0; l < 12; ++l) {
                // compile-time indices after unroll -> stays in registers
                const float wl = (&wq[3 * u + (l >> 2)].x)[l & 3];
                acc0[l] += C3a * wl;
                acc1[l] += C3b * wl;
            }

            float A3 = (s1 + di * (1.f / 3.f)) * 0.5f;
            float C2 = s2 + dj * A3;
            s3a += dka * C2;
            s3b += dkb * C2;
            s2  += dj * (s1 + 0.5f * di);
            s1  += di;
        }
    }

    if (t < 432) {
        float* ob = out + (size_t)b * OUT_PER_B;
        if (j == 0 && kh == 0) ob[i] = s1;                 // level 1
        if (kh == 0) ob[12 + i * 12 + j] = s2;             // level 2
        const int ijk = (i * 12 + j) * 12 + k0;
        ob[156 + ijk]     = s3a;                           // level 3
        ob[156 + ijk + 1] = s3b;
        float4* o4 = (float4*)(ob + 1884 + (size_t)ijk * 12);  // level 4, 96B
        o4[0] = make_float4(acc0[0], acc0[1], acc0[2],  acc0[3]);
        o4[1] = make_float4(acc0[4], acc0[5], acc0[6],  acc0[7]);
        o4[2] = make_float4(acc0[8], acc0[9], acc0[10], acc0[11]);
        o4[3] = make_float4(acc1[0], acc1[1], acc1[2],  acc1[3]);
        o4[4] = make_float4(acc1[4], acc1[5], acc1[6],  acc1[7]);
        o4[5] = make_float4(acc1[8], acc1[9], acc1[10], acc1[11]);
    }
}

extern "C" void kernel_launch(void* const* d_in, const int* in_sizes, int n_in,
                              void* d_out, int out_size, void* d_ws, size_t ws_size,
                              hipStream_t stream) {
    const float* path = (const float*)d_in[0];
    float* out = (float*)d_out;
    const int nbatch = in_sizes[0] / (NPTS * NC);   // = 128

    sig_kernel<<<nbatch * 2, BT, 0, stream>>>(path, out);
}